// Round 1
// 2556.737 us; speedup vs baseline: 1.7362x; 1.7362x over previous
//
#include <hip/hip_runtime.h>
#include <math.h>

#define DM   512     // d_model (== INPUT)
#define DI   1024    // d_inner
#define NS   16      // d_state
#define DTR  32      // dt_rank
#define LSEQ 4096
#define NB   8
#define T    8       // sub-tile timesteps
#define THR  512     // threads per chunk block

typedef float f32x2 __attribute__((ext_vector_type(2)));

__device__ __forceinline__ float siluf(float x) { return x / (1.f + __expf(-x)); }
__device__ __forceinline__ float softplusf(float x) {
  return (x > 20.f) ? x : log1pf(__expf(x));
}

// ---------------------------------------------------------------------------
// W2T[i][d] = sum_j in_w[d][j] * proj_w[j][i]   (stored TRANSPOSED: [DM][DI])
// 64x64 tile GEMM, transposed store.
// ---------------------------------------------------------------------------
__global__ __launch_bounds__(256) void foldW2T_k(
    const float* __restrict__ A,   // in_w_f[:DI]  (DI x DM)
    const float* __restrict__ B,   // proj_w       (DM x DM)
    float* __restrict__ CT) {      // W2T          (DM x DI)
  __shared__ __align__(16) float As[16][68];
  __shared__ __align__(16) float Bs[16][68];
  const int bm = blockIdx.y * 64, bn = blockIdx.x * 64;
  const int tid = threadIdx.x;
  const int tx = tid & 15, ty = tid >> 4;
  const int lr = tid >> 2, lc = (tid & 3) * 4;
  const int kk = tid >> 4, nn = (tid & 15) * 4;
  float acc[4][4] = {};
  for (int k0 = 0; k0 < DM; k0 += 16) {
    const float4 av = *reinterpret_cast<const float4*>(
        A + (size_t)(bm + lr) * DM + k0 + lc);
    const float4 bv = *reinterpret_cast<const float4*>(
        B + (size_t)(k0 + kk) * DM + bn + nn);
    __syncthreads();
    As[lc + 0][lr] = av.x; As[lc + 1][lr] = av.y;
    As[lc + 2][lr] = av.z; As[lc + 3][lr] = av.w;
    Bs[kk][nn + 0] = bv.x; Bs[kk][nn + 1] = bv.y;
    Bs[kk][nn + 2] = bv.z; Bs[kk][nn + 3] = bv.w;
    __syncthreads();
#pragma unroll
    for (int k = 0; k < 16; ++k) {
      const float4 a4 = *reinterpret_cast<const float4*>(&As[k][ty * 4]);
      const float4 b4 = *reinterpret_cast<const float4*>(&Bs[k][tx * 4]);
      float a[4] = {a4.x, a4.y, a4.z, a4.w};
      float b[4] = {b4.x, b4.y, b4.z, b4.w};
#pragma unroll
      for (int i = 0; i < 4; ++i)
#pragma unroll
        for (int j = 0; j < 4; ++j) acc[i][j] = fmaf(a[i], b[j], acc[i][j]);
    }
  }
  // transposed store: CT[i_col][d_row]
#pragma unroll
  for (int i = 0; i < 4; ++i)
#pragma unroll
    for (int j = 0; j < 4; ++j)
      CT[(size_t)(bn + tx * 4 + j) * DI + (bm + ty * 4 + i)] = acc[i][j];
}

// b2[d] = sum_j in_w[d,j] * proj_b[j]
__global__ __launch_bounds__(256) void foldb2_k(
    const float* __restrict__ in_w, const float* __restrict__ pb,
    float* __restrict__ b2) {
  __shared__ float pbs[DM];
  const int t = threadIdx.x;
  for (int i = t; i < DM; i += 256) pbs[i] = pb[i];
  __syncthreads();
  const int d = blockIdx.x * 256 + t;
  const float* wr = in_w + (size_t)d * DM;
  float s = 0.f;
  for (int k = 0; k < DM; k += 4) {
    const float4 wv = *reinterpret_cast<const float4*>(wr + k);
    s = fmaf(pbs[k], wv.x, s);     s = fmaf(pbs[k + 1], wv.y, s);
    s = fmaf(pbs[k + 2], wv.z, s); s = fmaf(pbs[k + 3], wv.w, s);
  }
  b2[d] = s;
}

// xprojB[kb*64+n] = float4{ xproj_w[n][4kb+j] }  (kb<DI/4, n<64)
__global__ __launch_bounds__(256) void xprojB_k(
    const float* __restrict__ xproj_w, float4* __restrict__ out) {
  const int id = blockIdx.x * 256 + threadIdx.x;  // < (DI/4)*64
  const int kb = id >> 6, n = id & 63;
  float4 v;
  v.x = xproj_w[(size_t)n * DI + 4 * kb + 0];
  v.y = xproj_w[(size_t)n * DI + 4 * kb + 1];
  v.z = xproj_w[(size_t)n * DI + 4 * kb + 2];
  v.w = xproj_w[(size_t)n * DI + 4 * kb + 3];
  out[id] = v;
}

// dtwT[r][d] = dt_w[d][r]
__global__ __launch_bounds__(256) void dtwT_k(
    const float* __restrict__ dt_w, float* __restrict__ out) {
  const int id = blockIdx.x * 256 + threadIdx.x;  // < DTR*DI
  const int r = id >> 10, d = id & (DI - 1);
  out[id] = dt_w[(size_t)d * DTR + r];
}

// ---------------------------------------------------------------------------
// xa for 2 channels over ROWS timesteps (coalesced W2T float2 loads).
// Fully unrolled constant indices -> SROA keeps a0/a1 in registers.
// ---------------------------------------------------------------------------
template <int ROWS>
__device__ __forceinline__ void xa_rows(
    const float* __restrict__ W2T, const float (&xs)[T][DM], int d0,
    float bb0, float bb1, float (&a0)[T], float (&a1)[T]) {
#pragma unroll
  for (int t = 0; t < ROWS; ++t) { a0[t] = bb0; a1[t] = bb1; }
  for (int k0 = 0; k0 < DM; k0 += 4) {
    const float2 w0 = *reinterpret_cast<const float2*>(W2T + (size_t)(k0 + 0) * DI + d0);
    const float2 w1 = *reinterpret_cast<const float2*>(W2T + (size_t)(k0 + 1) * DI + d0);
    const float2 w2 = *reinterpret_cast<const float2*>(W2T + (size_t)(k0 + 2) * DI + d0);
    const float2 w3 = *reinterpret_cast<const float2*>(W2T + (size_t)(k0 + 3) * DI + d0);
#pragma unroll
    for (int t = 0; t < ROWS; ++t) {
      const float4 xv = *reinterpret_cast<const float4*>(&xs[t][k0]);
      a0[t] = fmaf(xv.x, w0.x, a0[t]); a1[t] = fmaf(xv.x, w0.y, a1[t]);
      a0[t] = fmaf(xv.y, w1.x, a0[t]); a1[t] = fmaf(xv.y, w1.y, a1[t]);
      a0[t] = fmaf(xv.z, w2.x, a0[t]); a1[t] = fmaf(xv.z, w2.y, a1[t]);
      a0[t] = fmaf(xv.w, w3.x, a0[t]); a1[t] = fmaf(xv.w, w3.y, a1[t]);
    }
  }
}

// ---------------------------------------------------------------------------
// Fused chunk kernel. Block = (chunk c, batch b), 512 threads, 2 ch/thread.
// launch_bounds(THR,1): do NOT cap registers -- the (THR,4) variant spilled
// ~20-30 regs to scratch (2.9 GB writes + ~3 GB reads of scratch traffic per
// dispatch, VGPR_Count=64 vs ~110 live). Ac is recomputed per sub-tile to
// shrink the persistent live set by 32 regs.
// ---------------------------------------------------------------------------
__global__ __launch_bounds__(THR, 1) void chunk_k(
    const float* __restrict__ x, const float* __restrict__ W2T,
    const float* __restrict__ b2, const float* __restrict__ conv_w,
    const float* __restrict__ conv_b, const float4* __restrict__ xprojB,
    const float* __restrict__ dtwT, const float* __restrict__ dt_b,
    const float* __restrict__ A_log, float* __restrict__ sdtbuf,
    float* __restrict__ Sbuf, float* __restrict__ clb,
    float* __restrict__ xclast, int NCHR, int LCr) {
  __shared__ __align__(16) float xs[T][DM];    // 16 KB
  __shared__ __align__(16) float xcs[T][DI];   // 32 KB
  __shared__ __align__(16) float xdbs[T][72];  // 2.25 KB

  const int tid = threadIdx.x;
  const int c = blockIdx.x, b = blockIdx.y;
  const int t0 = c * LCr;
  const int d0 = tid * 2;   // this thread owns channels d0, d0+1

  float cw0[4], cw1[4];
#pragma unroll
  for (int k = 0; k < 4; ++k) {
    cw0[k] = conv_w[d0 * 4 + k];
    cw1[k] = conv_w[(d0 + 1) * 4 + k];
  }
  const float cb0 = conv_b[d0], cb1 = conv_b[d0 + 1];
  const float dtb0 = dt_b[d0], dtb1 = dt_b[d0 + 1];
  const float bb0 = b2[d0], bb1 = b2[d0 + 1];

  float S0[NS], S1[NS];
  float sdt0 = 0.f, sdt1 = 0.f;
#pragma unroll
  for (int n = 0; n < NS; ++n) { S0[n] = 0.f; S1[n] = 0.f; }

  auto fill_xs = [&](int grow, int rows) {
    const int tot = rows * (DM / 4);
    for (int i = tid; i < tot; i += THR) {
      const int r = i >> 7, kk = (i & 127) * 4;
      *reinterpret_cast<float4*>(&xs[r][kk]) =
          *reinterpret_cast<const float4*>(x + ((size_t)grow + r) * DM + kk);
    }
  };

  // ---- pre-stage: conv carries (pre-conv xa at t0-3..t0-1) ----
  float cx0[3] = {0.f, 0.f, 0.f}, cx1[3] = {0.f, 0.f, 0.f};
  if (c > 0) {
    fill_xs(b * LSEQ + t0 - 3, 3);
    __syncthreads();
    float a0[T], a1[T];
    xa_rows<3>(W2T, xs, d0, bb0, bb1, a0, a1);
    cx0[0] = a0[0]; cx0[1] = a0[1]; cx0[2] = a0[2];
    cx1[0] = a1[0]; cx1[1] = a1[1]; cx1[2] = a1[2];
  }

  // ---- main loop over sub-tiles ----
  for (int tt = 0; tt < LCr; tt += T) {
    const int grow = b * LSEQ + t0 + tt;
    __syncthreads();
    fill_xs(grow, T);
    __syncthreads();
    {
      float a0[T], a1[T];
      xa_rows<T>(W2T, xs, d0, bb0, bb1, a0, a1);
#pragma unroll
      for (int t = 0; t < T; ++t) {
        const float o0 = cb0 + cw0[0] * cx0[0] + cw0[1] * cx0[1] +
                         cw0[2] * cx0[2] + cw0[3] * a0[t];
        cx0[0] = cx0[1]; cx0[1] = cx0[2]; cx0[2] = a0[t];
        xcs[t][d0] = siluf(o0);
        const float o1 = cb1 + cw1[0] * cx1[0] + cw1[1] * cx1[1] +
                         cw1[2] * cx1[2] + cw1[3] * a1[t];
        cx1[0] = cx1[1]; cx1[1] = cx1[2]; cx1[2] = a1[t];
        xcs[t][d0 + 1] = siluf(o1);
      }
    }
    __syncthreads();
    // xdb: thread (t = tid>>6, n = tid&63); xprojB loads coalesced 16B/lane
    {
      const int t = tid >> 6;
      const int n0 = tid & 63;
      float s = 0.f;
      for (int kb = 0; kb < DI / 4; ++kb) {
        const float4 wv = xprojB[kb * 64 + n0];
        const float4 xv = *reinterpret_cast<const float4*>(&xcs[t][kb * 4]);
        s = fmaf(xv.x, wv.x, s); s = fmaf(xv.y, wv.y, s);
        s = fmaf(xv.z, wv.z, s); s = fmaf(xv.w, wv.w, s);
      }
      xdbs[t][n0] = s;
    }
    __syncthreads();
    // dt + scan partial update (2 channels per thread), dtwT coalesced
    {
      float raw0[T], raw1[T];
#pragma unroll
      for (int t = 0; t < T; ++t) { raw0[t] = dtb0; raw1[t] = dtb1; }
      for (int r0 = 0; r0 < DTR; r0 += 4) {
        const float2 u0 = *reinterpret_cast<const float2*>(dtwT + (size_t)(r0 + 0) * DI + d0);
        const float2 u1 = *reinterpret_cast<const float2*>(dtwT + (size_t)(r0 + 1) * DI + d0);
        const float2 u2 = *reinterpret_cast<const float2*>(dtwT + (size_t)(r0 + 2) * DI + d0);
        const float2 u3 = *reinterpret_cast<const float2*>(dtwT + (size_t)(r0 + 3) * DI + d0);
#pragma unroll
        for (int t = 0; t < T; ++t) {
          const float4 bv = *reinterpret_cast<const float4*>(&xdbs[t][r0]);
          raw0[t] = fmaf(bv.x, u0.x, raw0[t]); raw1[t] = fmaf(bv.x, u0.y, raw1[t]);
          raw0[t] = fmaf(bv.y, u1.x, raw0[t]); raw1[t] = fmaf(bv.y, u1.y, raw1[t]);
          raw0[t] = fmaf(bv.z, u2.x, raw0[t]); raw1[t] = fmaf(bv.z, u2.y, raw1[t]);
          raw0[t] = fmaf(bv.w, u3.x, raw0[t]); raw1[t] = fmaf(bv.w, u3.y, raw1[t]);
        }
      }
      // Ac recomputed here (phase-local live range instead of kernel-wide)
      float Ac0[NS], Ac1[NS];
#pragma unroll
      for (int n = 0; n < NS; n += 4) {
        const float4 av0 = *reinterpret_cast<const float4*>(A_log + (size_t)d0 * NS + n);
        const float4 av1 = *reinterpret_cast<const float4*>(A_log + (size_t)(d0 + 1) * NS + n);
        Ac0[n + 0] = -__expf(av0.x); Ac0[n + 1] = -__expf(av0.y);
        Ac0[n + 2] = -__expf(av0.z); Ac0[n + 3] = -__expf(av0.w);
        Ac1[n + 0] = -__expf(av1.x); Ac1[n + 1] = -__expf(av1.y);
        Ac1[n + 2] = -__expf(av1.z); Ac1[n + 3] = -__expf(av1.w);
      }
#pragma unroll
      for (int t = 0; t < T; ++t) {
        const float dtv0 = softplusf(raw0[t]);
        const float dtv1 = softplusf(raw1[t]);
        sdt0 += dtv0;
        sdt1 += dtv1;
        const float w0 = dtv0 * xcs[t][d0];
        const float w1 = dtv1 * xcs[t][d0 + 1];
#pragma unroll
        for (int n = 0; n < NS; ++n) {
          const float Bn = xdbs[t][DTR + n];
          S0[n] = fmaf(S0[n], __expf(dtv0 * Ac0[n]), w0 * Bn);
          S1[n] = fmaf(S1[n], __expf(dtv1 * Ac1[n]), w1 * Bn);
        }
      }
    }
  }

  // ---- epilogue: store chunk partials (non-temporal: keep L2 for weights) --
  {
    f32x2 sv; sv.x = sdt0; sv.y = sdt1;
    __builtin_nontemporal_store(
        sv, reinterpret_cast<f32x2*>(sdtbuf + ((size_t)b * NCHR + c) * DI + d0));
#pragma unroll
    for (int n = 0; n < NS; ++n) {
      f32x2 v; v.x = S0[n]; v.y = S1[n];
      __builtin_nontemporal_store(
          v, reinterpret_cast<f32x2*>(
                 Sbuf + (((size_t)b * NCHR + c) * NS + n) * DI + d0));
    }
  }
  if (c == NCHR - 1) {
    xclast[(size_t)b * DI + d0] = xcs[T - 1][d0];
    xclast[(size_t)b * DI + d0 + 1] = xcs[T - 1][d0 + 1];
    if (tid < NS) clb[b * NS + tid] = xdbs[T - 1][DTR + NS + tid];
  }
}

// ---------------------------------------------------------------------------
// Fold chunk partials: h = fold over chunks, y = h.C_last + xc_last*D
// ---------------------------------------------------------------------------
__global__ __launch_bounds__(256) void fold_k(
    const float* __restrict__ sdt, const float* __restrict__ Sb,
    const float* __restrict__ A_log, const float* __restrict__ clb,
    const float* __restrict__ xclast, const float* __restrict__ Dw,
    float* __restrict__ y, int NCHR) {
  const int tid = blockIdx.x * 256 + threadIdx.x;
  const int b = tid >> 10, d = tid & (DI - 1);
  float Ac[NS], h[NS];
#pragma unroll
  for (int n = 0; n < NS; ++n) {
    Ac[n] = -__expf(A_log[d * NS + n]);
    h[n] = 0.f;
  }
  for (int c = 0; c < NCHR; ++c) {
    const float s = sdt[((size_t)b * NCHR + c) * DI + d];
#pragma unroll
    for (int n = 0; n < NS; ++n)
      h[n] = fmaf(h[n], __expf(Ac[n] * s),
                  Sb[(((size_t)b * NCHR + c) * NS + n) * DI + d]);
  }
  float acc = 0.f;
#pragma unroll
  for (int n = 0; n < NS; ++n) acc += h[n] * clb[b * NS + n];
  y[(size_t)b * DI + d] = acc + xclast[(size_t)b * DI + d] * Dw[d];
}

// ---------------------------------------------------------------------------
__device__ __forceinline__ float dotf(const float* lds, const float* w, int n) {
  float s = 0.f;
#pragma unroll 4
  for (int k = 0; k < n; k += 4) {
    const float4 wv = *reinterpret_cast<const float4*>(w + k);
    s = fmaf(lds[k], wv.x, s);
    s = fmaf(lds[k + 1], wv.y, s);
    s = fmaf(lds[k + 2], wv.z, s);
    s = fmaf(lds[k + 3], wv.w, s);
  }
  return s;
}

// Tail: all last-token-only work (fwd gate, entire bwd branch, out/fusion/LN).
__global__ __launch_bounds__(512) void tail_k(
    const float* __restrict__ x, const float* __restrict__ proj_w,
    const float* __restrict__ proj_b, const float* __restrict__ ybuf,
    const float* in_w_f, const float* out_w_f, const float* in_w_b,
    const float* conv_w_b, const float* conv_b_b, const float* xproj_w_b,
    const float* dt_w_b, const float* dt_b_b, const float* D_b,
    const float* out_w_b, const float* fusion_w, const float* fusion_b,
    const float* ln_g, const float* ln_b, float* __restrict__ out) {
  __shared__ float xls[DM];
  __shared__ float xpL[DM];
  __shared__ float xcb[DI];
  __shared__ float zb[DI];
  __shared__ float zf[DI];
  __shared__ float gf[DI];
  __shared__ float gb[DI];
  __shared__ float cat[DI];
  __shared__ float xdbb[64];
  __shared__ float red[DM];
  __shared__ float mu_s, var_s;
  const int b = blockIdx.x, t = threadIdx.x;

  xls[t] = x[((size_t)b * LSEQ + (LSEQ - 1)) * DM + t];
  __syncthreads();
  xpL[t] = proj_b[t] + dotf(xls, proj_w + (size_t)t * DM, DM);
  __syncthreads();

  for (int q = 0; q < 4; ++q) {
    int i = q * 512 + t;
    float s = dotf(xpL, in_w_b + (size_t)i * DM, DM);
    if (i < DI) {
      xcb[i] = siluf(s * conv_w_b[i * 4 + 3] + conv_b_b[i]);
    } else {
      zb[i - DI] = s;
    }
  }
  for (int q = 0; q < 2; ++q) {
    int d = q * 512 + t;
    zf[d] = dotf(xpL, in_w_f + (size_t)(DI + d) * DM, DM);
  }
  __syncthreads();

  if (t < 64) xdbb[t] = dotf(xcb, xproj_w_b + (size_t)t * DI, DI);
  __syncthreads();

  float bc = 0.f;
#pragma unroll
  for (int n = 0; n < NS; ++n) bc += xdbb[DTR + n] * xdbb[DTR + NS + n];

  for (int q = 0; q < 2; ++q) {
    int d = q * 512 + t;
    float raw = dt_b_b[d];
    const float* wr = dt_w_b + (size_t)d * DTR;
#pragma unroll
    for (int r = 0; r < DTR; ++r) raw = fmaf(xdbb[r], wr[r], raw);
    float dtv = softplusf(raw);
    float yb = dtv * xcb[d] * bc + xcb[d] * D_b[d];
    gb[d] = yb * siluf(zb[d]);
    gf[d] = ybuf[(size_t)b * DI + d] * siluf(zf[d]);
  }
  __syncthreads();

  cat[t] = dotf(gf, out_w_f + (size_t)t * DI, DI);
  cat[DM + t] = dotf(gb, out_w_b + (size_t)t * DI, DI);
  __syncthreads();

  float rv = fusion_b[t] + dotf(cat, fusion_w + (size_t)t * DI, DI);

  red[t] = rv;
  __syncthreads();
  for (int s = 256; s > 0; s >>= 1) {
    if (t < s) red[t] += red[t + s];
    __syncthreads();
  }
  if (t == 0) mu_s = red[0] * (1.f / DM);
  __syncthreads();
  float dv = rv - mu_s;
  red[t] = dv * dv;
  __syncthreads();
  for (int s = 256; s > 0; s >>= 1) {
    if (t < s) red[t] += red[t + s];
    __syncthreads();
  }
  if (t == 0) var_s = red[0] * (1.f / DM);
  __syncthreads();
  out[(size_t)b * DM + t] = dv * rsqrtf(var_s + 1e-5f) * ln_g[t] + ln_b[t];
}

// ---------------------------------------------------------------------------
static size_t plan_need(int nch, size_t* offs) {
  size_t o = 0;
  int idx = 0;
  auto al = [&](size_t n) {
    size_t q = (o + 255) & ~(size_t)255;
    o = q + n;
    if (offs) offs[idx] = q;
    ++idx;
  };
  al((size_t)DM * DI * 4);               // 0: W2T
  al((size_t)DI * 4);                    // 1: b2
  al((size_t)(DI / 4) * 64 * 16);        // 2: xprojB
  al((size_t)DTR * DI * 4);              // 3: dtwT
  al((size_t)NB * DI * 4);               // 4: y
  al((size_t)NB * nch * DI * 4);         // 5: sdt
  al((size_t)NB * NS * 4);               // 6: clb
  al((size_t)NB * DI * 4);               // 7: xclast
  al((size_t)NB * nch * NS * DI * 4);    // 8: Sb
  return o;
}

extern "C" void kernel_launch(void* const* d_in, const int* in_sizes, int n_in,
                              void* d_out, int out_size, void* d_ws,
                              size_t ws_size, hipStream_t stream) {
  (void)in_sizes; (void)n_in; (void)out_size;
  const float* x        = (const float*)d_in[0];
  const float* proj_w   = (const float*)d_in[1];
  const float* proj_b   = (const float*)d_in[2];
  const float* in_w_f   = (const float*)d_in[3];
  const float* conv_w_f = (const float*)d_in[4];
  const float* conv_b_f = (const float*)d_in[5];
  const float* xproj_w_f= (const float*)d_in[6];
  const float* dt_w_f   = (const float*)d_in[7];
  const float* dt_b_f   = (const float*)d_in[8];
  const float* A_log_f  = (const float*)d_in[9];
  const float* D_f      = (const float*)d_in[10];
  const float* out_w_f  = (const float*)d_in[11];
  const float* in_w_b   = (const float*)d_in[12];
  const float* conv_w_b = (const float*)d_in[13];
  const float* conv_b_b = (const float*)d_in[14];
  const float* xproj_w_b= (const float*)d_in[15];
  const float* dt_w_b   = (const float*)d_in[16];
  const float* dt_b_b   = (const float*)d_in[17];
  // d_in[18] = A_log_b unused (bwd branch only needs t=0, where h0 = 0)
  const float* D_b      = (const float*)d_in[19];
  const float* out_w_b  = (const float*)d_in[20];
  const float* fusion_w = (const float*)d_in[21];
  const float* fusion_b = (const float*)d_in[22];
  const float* ln_g     = (const float*)d_in[23];
  const float* ln_b     = (const float*)d_in[24];

  // Ladder (host-constant wrt ws_size -> graph-safe). R6 proved ws >= 35.7MB.
  int NCHR;
  if (ws_size >= plan_need(128, nullptr)) NCHR = 128;
  else if (ws_size >= plan_need(64, nullptr)) NCHR = 64;
  else NCHR = 32;
  const int LCr = LSEQ / NCHR;

  size_t offs[9];
  plan_need(NCHR, offs);
  char* base = (char*)d_ws;
  float*  W2T    = (float*)(base + offs[0]);
  float*  b2     = (float*)(base + offs[1]);
  float4* xprojB = (float4*)(base + offs[2]);
  float*  dtwT   = (float*)(base + offs[3]);
  float*  y      = (float*)(base + offs[4]);
  float*  sdt    = (float*)(base + offs[5]);
  float*  clb    = (float*)(base + offs[6]);
  float*  xclast = (float*)(base + offs[7]);
  float*  Sb     = (float*)(base + offs[8]);

  foldb2_k<<<dim3(DI / 256), dim3(256), 0, stream>>>(in_w_f, proj_b, b2);
  foldW2T_k<<<dim3(DM / 64, DI / 64), dim3(256), 0, stream>>>(in_w_f, proj_w, W2T);
  xprojB_k<<<dim3((DI / 4) * 64 / 256), dim3(256), 0, stream>>>(xproj_w_f, xprojB);
  dtwT_k<<<dim3(DTR * DI / 256), dim3(256), 0, stream>>>(dt_w_f, dtwT);
  chunk_k<<<dim3(NCHR, NB), dim3(THR), 0, stream>>>(
      x, W2T, b2, conv_w_f, conv_b_f, xprojB, dtwT, dt_b_f, A_log_f,
      sdt, Sb, clb, xclast, NCHR, LCr);
  fold_k<<<dim3((NB * DI) / 256), dim3(256), 0, stream>>>(
      sdt, Sb, A_log_f, clb, xclast, D_f, y, NCHR);
  tail_k<<<dim3(NB), dim3(512), 0, stream>>>(
      x, proj_w, proj_b, y, in_w_f, out_w_f, in_w_b, conv_w_b, conv_b_b,
      xproj_w_b, dt_w_b, dt_b_b, D_b, out_w_b, fusion_w, fusion_b, ln_g, ln_b,
      (float*)d_out);
}